// Round 18
// baseline (116.605 us; speedup 1.0000x reference)
//
#include <hip/hip_runtime.h>
#include <hip/hip_bf16.h>

// Problem constants
constexpr int Bc  = 2;
constexpr int Tc  = 2048;
constexpr int Ec  = 1024;
constexpr int Hc  = 16;
constexpr int KVc = 4;
constexpr int Dc  = 64;
// G = Hc/KVc = 4

typedef short bf16x8 __attribute__((ext_vector_type(8)));
typedef short short4v __attribute__((ext_vector_type(4)));
typedef float f32x4  __attribute__((ext_vector_type(4)));
typedef float f32x16 __attribute__((ext_vector_type(16)));
typedef int   i32x4  __attribute__((ext_vector_type(4)));

__device__ inline short f2bf_bits(float f) {
    union { __hip_bfloat16 h; short s; } u;
    u.h = __float2bfloat16(f);
    return u.s;
}

__device__ inline float bf2f(short s) {
    union { short s16; __hip_bfloat16 h; } u;
    u.s16 = s;
    return __bfloat162float(u.h);
}

__device__ inline unsigned pkbf(float a, float b) {
    union { __hip_bfloat162 h2; unsigned u; } u;
    u.h2 = __float22bfloat162_rn(float2{a, b});
    return u.u;
}

__device__ inline float fexp2(float x) { return __builtin_exp2f(x); }

// v_permlane32_swap_b32 a, b:  a' = [a.lo | b.lo], b' = [a.hi | b.hi].
// ONLY safe when a and b hold provably-distinct values (round-8 lesson:
// equal inputs get register-coalesced and the swap corrupts).
__device__ inline void permswap(unsigned &a, unsigned &b) {
    asm volatile("v_permlane32_swap_b32 %0, %1" : "+v"(a), "+v"(b));
}

// global -> LDS async copy, 16B per lane. LDS dest must be wave-uniform base;
// HW writes base + lane*16. Global src is per-lane (pre-swizzled).
__device__ inline void gload16(const short* g, short* lds) {
    __builtin_amdgcn_global_load_lds(
        (const __attribute__((address_space(1))) unsigned int*)g,
        (__attribute__((address_space(3))) unsigned int*)lds,
        16, 0, 0);
}

// ---------------------------------------------------------------------------
// fp32 -> bf16 convert for QUERY only (key/value conversion is fused into
// the projection GEMM's A-staging — their A panels are re-read only 4x).
// ---------------------------------------------------------------------------
__global__ __launch_bounds__(256) void conv_q(
    const float* __restrict__ q, short* __restrict__ Xq)
{
    int i = (blockIdx.x * 256 + threadIdx.x) * 4;
    float4 vv = *reinterpret_cast<const float4*>(q + i);
    short4v o;
    o[0] = f2bf_bits(vv.x);
    o[1] = f2bf_bits(vv.y);
    o[2] = f2bf_bits(vv.z);
    o[3] = f2bf_bits(vv.w);
    *reinterpret_cast<short4v*>(Xq + i) = o;
}

// ---------------------------------------------------------------------------
// merged transpose + convert: W[K][N] fp32 -> Wt[N][K] bf16, all 4 weights
// ---------------------------------------------------------------------------
__global__ __launch_bounds__(256) void transp_all(
    const float* __restrict__ Wq, const float* __restrict__ Wk,
    const float* __restrict__ Wv, const float* __restrict__ Wo,
    short* __restrict__ Wqt, short* __restrict__ Wkt,
    short* __restrict__ Wvt, short* __restrict__ Wot)
{
    __shared__ float tile[32][33];
    const int id = blockIdx.x;
    const float* W; short* Wt; int N, bx, by;
    if (id < 1024)      { W = Wq; Wt = Wqt; N = 1024; bx = id & 31;          by = id >> 5; }
    else if (id < 1280) { W = Wk; Wt = Wkt; N = 256;  bx = (id - 1024) & 7;  by = (id - 1024) >> 3; }
    else if (id < 1536) { W = Wv; Wt = Wvt; N = 256;  bx = (id - 1280) & 7;  by = (id - 1280) >> 3; }
    else                { W = Wo; Wt = Wot; N = 1024; bx = (id - 1536) & 31; by = (id - 1536) >> 5; }
    const int K = 1024;
    int nb = bx * 32, kb = by * 32;
    int tx = threadIdx.x & 31, ty = threadIdx.x >> 5;   // ty 0..7
    #pragma unroll
    for (int j = 0; j < 4; ++j)
        tile[ty + j * 8][tx] = W[(size_t)(kb + ty + j * 8) * N + nb + tx];
    __syncthreads();
    #pragma unroll
    for (int j = 0; j < 4; ++j)
        Wt[(size_t)(nb + ty + j * 8) * K + kb + tx] = f2bf_bits(tile[tx][ty + j * 8]);
}

// ---------------------------------------------------------------------------
// Grouped Q/K/V projection GEMM, 128x64 tile, BK=64, 4 waves.
// mode 0 (Q): A = bf16 Xq via global_load_lds.
// modes 1/2 (K/V): A = fp32 key/value, reg-staged with fused bf16 convert
//   (same swizzled LDS layout; fp32 panels re-read 4x, L2/L3-absorbed).
// Fused RoPE epilogue for Q and K; V stored transposed.
// ---------------------------------------------------------------------------
__global__ __launch_bounds__(256) void gemm_qkv(
    const short* __restrict__ Xq,
    const float* __restrict__ keyF, const float* __restrict__ valF,
    const short* __restrict__ Wqt, const short* __restrict__ Wkt,
    const short* __restrict__ Wvt,
    const float* __restrict__ bq, const float* __restrict__ bk,
    const float* __restrict__ bv,
    const float* __restrict__ cosE, const float* __restrict__ sinE,
    short* __restrict__ Qp, short* __restrict__ Kp, short* __restrict__ VTp)
{
    __shared__ short As[128 * 64];
    __shared__ short Bs[64 * 64];
    const int gid = blockIdx.x;
    const short* Bt; const float* bias; int bx, by, mode;
    const float* Af = nullptr;
    if (gid < 512)      { mode = 0; Bt = Wqt; bias = bq; bx = gid & 15;        by = gid >> 4; }
    else if (gid < 640) { mode = 1; Af = keyF; Bt = Wkt; bias = bk; bx = (gid - 512) & 3; by = (gid - 512) >> 2; }
    else                { mode = 2; Af = valF; Bt = Wvt; bias = bv; bx = (gid - 640) & 3; by = (gid - 640) >> 2; }
    const int m0 = by * 128, n0 = bx * 64;

    const int lane = threadIdx.x & 63;
    const int w    = threadIdx.x >> 6;
    const int wm   = w >> 1, wn = w & 1;
    const int rin  = lane >> 3;
    const int swc  = ((lane & 7) ^ rin) * 8;

    f32x4 acc[4][2] = {};

    for (int k0 = 0; k0 < 1024; k0 += 64) {
        if (mode == 0) {
            #pragma unroll
            for (int i2 = 0; i2 < 4; ++i2) {
                const int r = w * 32 + i2 * 8;
                gload16(Xq + (size_t)(m0 + r + rin) * 1024 + k0 + swc, As + r * 64);
            }
        } else {
            // fp32 A: load + convert + swizzled LDS write (4 slots/thread)
            #pragma unroll
            for (int it = 0; it < 4; ++it) {
                int s   = threadIdx.x + it * 256;   // 1024 slots of 8 elems
                int row = s >> 3;
                int c8  = s & 7;
                const float* src = Af + (size_t)(m0 + row) * 1024 + k0 + c8 * 8;
                float4 f0 = *reinterpret_cast<const float4*>(src);
                float4 f1 = *reinterpret_cast<const float4*>(src + 4);
                union { unsigned u4[4]; bf16x8 v; } pk;
                pk.u4[0] = pkbf(f0.x, f0.y);
                pk.u4[1] = pkbf(f0.z, f0.w);
                pk.u4[2] = pkbf(f1.x, f1.y);
                pk.u4[3] = pkbf(f1.z, f1.w);
                *reinterpret_cast<bf16x8*>(As + row * 64 + ((c8 ^ (row & 7)) * 8)) = pk.v;
            }
        }
        #pragma unroll
        for (int i2 = 0; i2 < 2; ++i2) {
            const int r = w * 16 + i2 * 8;
            gload16(Bt + (size_t)(n0 + r + rin) * 1024 + k0 + swc, Bs + r * 64);
        }
        __syncthreads();
        #pragma unroll
        for (int ks = 0; ks < 2; ++ks) {
            bf16x8 af[4], bfr[2];
            #pragma unroll
            for (int mi = 0; mi < 4; ++mi) {
                int row = wm * 64 + mi * 16 + (lane & 15);
                int sl  = (ks * 4 + (lane >> 4)) ^ (row & 7);
                af[mi] = *reinterpret_cast<const bf16x8*>(As + row * 64 + sl * 8);
            }
            #pragma unroll
            for (int ni = 0; ni < 2; ++ni) {
                int row = wn * 32 + ni * 16 + (lane & 15);
                int sl  = (ks * 4 + (lane >> 4)) ^ (row & 7);
                bfr[ni] = *reinterpret_cast<const bf16x8*>(Bs + row * 64 + sl * 8);
            }
            #pragma unroll
            for (int mi = 0; mi < 4; ++mi)
                #pragma unroll
                for (int ni = 0; ni < 2; ++ni)
                    acc[mi][ni] = __builtin_amdgcn_mfma_f32_16x16x32_bf16(
                        af[mi], bfr[ni], acc[mi][ni], 0, 0, 0);
        }
        __syncthreads();
    }

    if (mode == 2) {
        // V: transposed store (no rope)
        #pragma unroll
        for (int mi = 0; mi < 4; ++mi)
            #pragma unroll
            for (int ni = 0; ni < 2; ++ni) {
                int col = n0 + wn * 32 + ni * 16 + (lane & 15);
                float bv2 = bias[col];
                #pragma unroll
                for (int i = 0; i < 4; ++i) {
                    int row = m0 + wm * 64 + mi * 16 + ((lane >> 4) * 4) + i;
                    VTp[(((size_t)(row >> 11) * 256 + col) << 11) + (row & 2047)]
                        = f2bf_bits(acc[mi][ni][i] + bv2);
                }
            }
        return;
    }

    // Q/K: dump tile (post-bias, bf16) into As, then fused rope.
    #pragma unroll
    for (int mi = 0; mi < 4; ++mi)
        #pragma unroll
        for (int ni = 0; ni < 2; ++ni) {
            int cl = wn * 32 + ni * 16 + (lane & 15);
            float bv2 = bias[n0 + cl];
            #pragma unroll
            for (int i = 0; i < 4; ++i) {
                int rl = wm * 64 + mi * 16 + ((lane >> 4) * 4) + i;
                As[rl * 64 + cl] = f2bf_bits(acc[mi][ni][i] + bv2);
            }
        }
    __syncthreads();

    const float scale = (mode == 0) ? 0.125f * 1.44269504089f : 1.0f;
    short* outp = (mode == 0) ? Qp : Kp;
    const int ldo = (mode == 0) ? 1024 : 256;
    const int dg  = (threadIdx.x & 7) * 4;     // d group 0..28
    const int rb  = threadIdx.x >> 3;          // row base 0..31
    #pragma unroll
    for (int rr = 0; rr < 4; ++rr) {
        int rl = rb + rr * 32;
        int t  = (m0 + rl) & (Tc - 1);
        float4 c4 = *reinterpret_cast<const float4*>(cosE + t * 64 + dg);
        float4 s4 = *reinterpret_cast<const float4*>(sinE + t * 64 + dg);
        short4v a = *reinterpret_cast<const short4v*>(As + rl * 64 + dg);
        short4v b = *reinterpret_cast<const short4v*>(As + rl * 64 + 32 + dg);
        float c[4] = {c4.x, c4.y, c4.z, c4.w};
        float s[4] = {s4.x, s4.y, s4.z, s4.w};
        short4v oa, ob;
        #pragma unroll
        for (int j = 0; j < 4; ++j) {
            float x1 = bf2f(a[j]), x2 = bf2f(b[j]);
            oa[j] = f2bf_bits((x1 * c[j] - x2 * s[j]) * scale);
            ob[j] = f2bf_bits((x2 * c[j] + x1 * s[j]) * scale);
        }
        size_t go = (size_t)(m0 + rl) * ldo + n0 + dg;
        *reinterpret_cast<short4v*>(outp + go)      = oa;
        *reinterpret_cast<short4v*>(outp + go + 32) = ob;
    }
}

// ---------------------------------------------------------------------------
// O-projection GEMM (bf16 A via gload_lds): attn @ Wot + bo -> fp32 out
// ---------------------------------------------------------------------------
__global__ __launch_bounds__(256) void gemm_o(
    const short* __restrict__ A, const short* __restrict__ Bt,
    const float* __restrict__ bias, float* __restrict__ C)
{
    __shared__ short As[128 * 64];
    __shared__ short Bs[64 * 64];
    const int m0 = blockIdx.y * 128, n0 = blockIdx.x * 64;

    const int lane = threadIdx.x & 63;
    const int w    = threadIdx.x >> 6;
    const int wm   = w >> 1, wn = w & 1;
    const int rin  = lane >> 3;
    const int swc  = ((lane & 7) ^ rin) * 8;

    f32x4 acc[4][2] = {};

    for (int k0 = 0; k0 < 1024; k0 += 64) {
        #pragma unroll
        for (int i2 = 0; i2 < 4; ++i2) {
            const int r = w * 32 + i2 * 8;
            gload16(A + (size_t)(m0 + r + rin) * 1024 + k0 + swc, As + r * 64);
        }
        #pragma unroll
        for (int i2 = 0; i2 < 2; ++i2) {
            const int r = w * 16 + i2 * 8;
            gload16(Bt + (size_t)(n0 + r + rin) * 1024 + k0 + swc, Bs + r * 64);
        }
        __syncthreads();
        #pragma unroll
        for (int ks = 0; ks < 2; ++ks) {
            bf16x8 af[4], bfr[2];
            #pragma unroll
            for (int mi = 0; mi < 4; ++mi) {
                int row = wm * 64 + mi * 16 + (lane & 15);
                int sl  = (ks * 4 + (lane >> 4)) ^ (row & 7);
                af[mi] = *reinterpret_cast<const bf16x8*>(As + row * 64 + sl * 8);
            }
            #pragma unroll
            for (int ni = 0; ni < 2; ++ni) {
                int row = wn * 32 + ni * 16 + (lane & 15);
                int sl  = (ks * 4 + (lane >> 4)) ^ (row & 7);
                bfr[ni] = *reinterpret_cast<const bf16x8*>(Bs + row * 64 + sl * 8);
            }
            #pragma unroll
            for (int mi = 0; mi < 4; ++mi)
                #pragma unroll
                for (int ni = 0; ni < 2; ++ni)
                    acc[mi][ni] = __builtin_amdgcn_mfma_f32_16x16x32_bf16(
                        af[mi], bfr[ni], acc[mi][ni], 0, 0, 0);
        }
        __syncthreads();
    }

    #pragma unroll
    for (int mi = 0; mi < 4; ++mi)
        #pragma unroll
        for (int ni = 0; ni < 2; ++ni) {
            int col = n0 + wn * 32 + ni * 16 + (lane & 15);
            float bv2 = bias[col];
            #pragma unroll
            for (int i = 0; i < 4; ++i) {
                int row = m0 + wm * 64 + mi * 16 + ((lane >> 4) * 4) + i;
                C[(size_t)row * 1024 + col] = acc[mi][ni][i] + bv2;
            }
        }
}

// ---------------------------------------------------------------------------
// Causal GQA flash attention (round-12 proven version, unchanged):
// per-slice K/V ds_reads (64 VGPR + 64 acc = 128 regs), permswap pack,
// launch_bounds(256,4) -> 4 waves/SIMD co-resident, 2-buffer staging.
// ---------------------------------------------------------------------------
__global__ __launch_bounds__(256, 4) void flash_gqa10(
    const short* __restrict__ Q,   // [B*T][H*D]  post-RoPE, pre-scaled
    const short* __restrict__ Kx,  // [B*T][KV*D] post-RoPE
    const short* __restrict__ VT,  // [B*KV][D][T]
    short* __restrict__ attn,      // [B*T][H*D]
    short* __restrict__ PO,        // partial O (bf16)
    float* __restrict__ ML)        // partial (m, l) f32
{
    __shared__ short smem[16384];  // 32KB: K dbuf [0,8192), V dbuf [8192,16384)

    const int lane = threadIdx.x & 63;
    const int w    = threadIdx.x >> 6;
    const int lo   = lane & 31;
    const int hi   = lane >> 5;

    // Decode: XCD owns one (b,kvh); j enumerates (g, chunk-unit), heavy first.
    const int L   = blockIdx.x;          // 0..1279
    const int xcd = L & 7;
    const int j   = L >> 3;              // 0..159
    const int g   = j & 3;
    const int u   = 39 - (j >> 2);       // 0..39, compact (qt, c) index
    int qt = 0, rem = u;
    while (true) { int nc0 = (qt >> 2) + 1; if (rem < nc0) break; rem -= nc0; ++qt; }
    const int c  = rem;
    const int nc = (qt >> 2) + 1;
    const int b   = xcd >> 2;
    const int kvh = xcd & 3;
    const int h   = kvh * 4 + g;
    const int slot = (b * 16 + h) * 40 + u;

    const int q0w = qt * 128 + w * 32;
    const int qg  = q0w + lo;

    // Q B-fragments (persistent, 16 VGPR)
    bf16x8 qf[4];
    {
        const short* qp = Q + (size_t)(b * Tc + qg) * Ec + h * 64 + hi * 8;
        #pragma unroll
        for (int ds = 0; ds < 4; ++ds)
            qf[ds] = *reinterpret_cast<const bf16x8*>(qp + 16 * ds);
    }
    const short* Kb = Kx + (size_t)b * Tc * (KVc * Dc) + kvh * 64;
    const short* Vb = VT + (size_t)(b * KVc + kvh) * 64 * Tc;

    const int rin = lane >> 3;
    const int swc = ((lane & 7) ^ rin) * 8;
    auto stage = [&](int bufi, int kb2) {
        #pragma unroll
        for (int i2 = 0; i2 < 2; ++i2) {
            const int row = w * 16 + i2 * 8;
            gload16(Kb + (size_t)(kb2 + row + rin) * 256 + swc,
                    smem + bufi * 4096 + row * 64);
            gload16(Vb + (size_t)(row + rin) * Tc + kb2 + swc,
                    smem + 8192 + bufi * 4096 + row * 64);
        }
    };

    // hoisted LDS fragment offsets: frag(a, i) at lo*64 + 2048*a + slot8[i]
    int slot8[4];
    #pragma unroll
    for (int i = 0; i < 4; ++i)
        slot8[i] = (((2 * i + hi) ^ (lo & 7)) * 8) + lo * 64;

    const int t0 = c * 8;
    const int t1 = min(c * 8 + 8, 2 * qt + 2);
    stage(0, t0 * 64);

    float m = -1e30f, l = 0.f;
    f32x16 o0 = {}, o1 = {};
    const int kv_hi = q0w + 32;

    for (int t = t0; t < t1; ++t) {
        const int kb  = t * 64;
        const int cur = (t - t0) & 1;
        // my tile-t rows landed; after barrier, everyone's have.
        asm volatile("s_waitcnt vmcnt(0)" ::: "memory");
        __builtin_amdgcn_s_barrier();
        // issue next tile (writes buf cur^1; all waves are past their reads of it)
        if (t + 1 < t1) stage(cur ^ 1, kb + 64);

        if (kb < kv_hi) {
            const short* Kl = smem + cur * 4096;
            const short* Vl = Kl + 8192;

            // S^T = K Q^T  (per-slice K loads: 8 transient regs)
            f32x16 s0 = {}, s1 = {};
            __builtin_amdgcn_s_setprio(1);
            #pragma unroll
            for (int ds = 0; ds < 4; ++ds) {
                bf16x8 k0 = *reinterpret_cast<const bf16x8*>(Kl + slot8[ds]);
                bf16x8 k1 = *reinterpret_cast<const bf16x8*>(Kl + slot8[ds] + 2048);
                s0 = __builtin_amdgcn_mfma_f32_32x32x16_bf16(k0, qf[ds], s0, 0, 0, 0);
                s1 = __builtin_amdgcn_mfma_f32_32x32x16_bf16(k1, qf[ds], s1, 0, 0, 0);
            }
            __builtin_amdgcn_s_setprio(0);

            // causal mask (diagonal tiles only)
            if (kb + 63 > q0w) {
                #pragma unroll
                for (int r = 0; r < 16; ++r) {
                    int kkl = (r & 3) + 8 * (r >> 2) + 4 * hi;
                    if (kb + kkl > qg)      s0[r] = -1e30f;
                    if (kb + 32 + kkl > qg) s1[r] = -1e30f;
                }
            }

            // online softmax: tree max, defer-max (T13), exp2 domain
            float mx[8];
            #pragma unroll
            for (int j2 = 0; j2 < 8; ++j2)
                mx[j2] = fmaxf(fmaxf(s0[2 * j2], s0[2 * j2 + 1]),
                               fmaxf(s1[2 * j2], s1[2 * j2 + 1]));
            #pragma unroll
            for (int st = 4; st > 0; st >>= 1)
                #pragma unroll
                for (int j2 = 0; j2 < st; ++j2) mx[j2] = fmaxf(mx[j2], mx[j2 + st]);
            float pm = fmaxf(mx[0], __shfl_xor(mx[0], 32));

            float corr = 1.0f;
            if (__any(pm > m + 8.0f)) {
                float mn = fmaxf(m, pm);
                corr = fexp2(m - mn);
                m = mn;
                #pragma unroll
                for (int r = 0; r < 16; ++r) { o0[r] *= corr; o1[r] *= corr; }
            }
            float rs = 0.f;
            #pragma unroll
            for (int r = 0; r < 16; ++r) {
                s0[r] = fexp2(s0[r] - m);
                s1[r] = fexp2(s1[r] - m);
                rs += s0[r] + s1[r];
            }
            rs += __shfl_xor(rs, 32);
            l = l * corr + rs;

            // pack P via permlane32_swap (distinct operands; 8 transient regs)
            // + per-slice V loads (8 transient regs) — keeps peak <= 128.
            #pragma unroll
            for (int t2 = 0; t2 < 2; ++t2) {
                const f32x16& sv = t2 ? s1 : s0;
                unsigned pw[8];
                #pragma unroll
                for (int j2 = 0; j2 < 8; ++j2)
                    pw[j2] = pkbf(sv[2 * j2], sv[2 * j2 + 1]);
                #pragma unroll
                for (int u2 = 0; u2 < 2; ++u2) {
                    permswap(pw[4 * u2 + 0], pw[4 * u2 + 2]);
                    permswap(pw[4 * u2 + 1], pw[4 * u2 + 3]);
                    union { unsigned u4[4]; bf16x8 v; } pf;
                    pf.u4[0] = pw[4 * u2 + 0];
                    pf.u4[1] = pw[4 * u2 + 1];
                    pf.u4[2] = pw[4 * u2 + 2];
                    pf.u4[3] = pw[4 * u2 + 3];
                    int sl = 2 * t2 + u2;
                    bf16x8 v0 = *reinterpret_cast<const bf16x8*>(Vl + slot8[sl]);
                    bf16x8 v1 = *reinterpret_cast<const bf16x8*>(Vl + slot8[sl] + 2048);
                    __builtin_amdgcn_s_setprio(1);
                    o0 = __builtin_amdgcn_mfma_f32_32x32x16_bf16(v0, pf.v, o0, 0, 0, 0);
                    o1 = __builtin_amdgcn_mfma_f32_32x32x16_bf16(v1, pf.v, o1, 0, 0, 0);
                    __builtin_amdgcn_s_setprio(0);
                }
            }
        }
    }
    // all waves past their final reads before obuf overwrites K/V region
    __builtin_amdgcn_s_barrier();

    // epilogue: transpose O^T via LDS -> coalesced global stores
    const float inv = (nc == 1) ? (1.0f / l) : 1.0f;
    short* ob = smem + w * 2048;
    #pragma unroll
    for (int r = 0; r < 16; ++r) {
        int d0 = (r & 3) + 8 * (r >> 2) + 4 * hi;
        ob[lo * 64 + ( d0       ^ ((lo & 7) << 3))] = f2bf_bits(o0[r] * inv);
        ob[lo * 64 + ((d0 + 32) ^ ((lo & 7) << 3))] = f2bf_bits(o1[r] * inv);
    }
    if (nc > 1 && hi == 0) {
        ML[(size_t)slot * 256 + (w * 32 + lo) * 2]     = m;
        ML[(size_t)slot * 256 + (w * 32 + lo) * 2 + 1] = l;
    }
    #pragma unroll
    for (int j2 = 0; j2 < 4; ++j2) {
        int row = lane >> 1;
        int c8  = ((lane & 1) * 4 + j2) * 8;
        bf16x8 v = *reinterpret_cast<const bf16x8*>(
            ob + row * 64 + (c8 ^ ((row & 7) << 3)));
        if (nc == 1)
            *reinterpret_cast<bf16x8*>(
                attn + (size_t)(b * Tc + q0w + row) * Ec + h * 64 + c8) = v;
        else
            *reinterpret_cast<bf16x8*>(
                PO + (size_t)slot * 8192 + (w * 32 + row) * 64 + c8) = v;
    }
}

// ---------------------------------------------------------------------------
// combine partials: for qt >= 4 merge nc chunks -> attn (vectorized).
// ---------------------------------------------------------------------------
__global__ __launch_bounds__(256) void combine_kernel(
    const short* __restrict__ PO, const float* __restrict__ ML,
    short* __restrict__ attn)
{
    const int qt    = 4 + (blockIdx.x >> 2);   // 4..15
    const int rg    = blockIdx.x & 3;          // row-group of 32
    const int combo = blockIdx.y;              // 0..31
    const int h = combo & 15, b = combo >> 4;
    const int nc = (qt >> 2) + 1;              // 2..4
    const int k  = qt >> 2, r4 = qt & 3;
    const int base = (k + 1) * (2 * k + r4);   // sum of nc for qt' < qt
    const int slot0 = combo * 40 + base;

    const int r  = rg * 32 + (threadIdx.x >> 3);   // row 0..127
    const int d8 = (threadIdx.x & 7) * 8;          // d group

    float mv[4], lv[4];
    float M = -1e30f;
    #pragma unroll 4
    for (int cc = 0; cc < nc; ++cc) {
        mv[cc] = ML[(size_t)(slot0 + cc) * 256 + r * 2];
        lv[cc] = ML[(size_t)(slot0 + cc) * 256 + r * 2 + 1];
        M = fmaxf(M, mv[cc]);
    }
    float Lsum = 0.f;
    float a[8] = {};
    #pragma unroll 4
    for (int cc = 0; cc < nc; ++cc) {
        float wgt = fexp2(mv[cc] - M);
        Lsum += wgt * lv[cc];
        bf16x8 po = *reinterpret_cast<const bf16x8*>(
            PO + (size_t)(slot0 + cc) * 8192 + r * 64 + d8);
        #pragma unroll
        for (int j = 0; j < 8; ++j) a[j] += wgt * bf2f(po[j]);
    }
    float inv = 1.0f / Lsum;
    bf16x8 o;
    #pragma unroll
    for (int j = 0; j < 8; ++j) o[j] = f2bf_bits(a[j] * inv);
    *reinterpret_cast<bf16x8*>(
        attn + (size_t)(b * Tc + qt * 128 + r) * Ec + h * 64 + d8) = o;
}

// ---------------------------------------------------------------------------
extern "C" void kernel_launch(void* const* d_in, const int* in_sizes, int n_in,
                              void* d_out, int out_size, void* d_ws, size_t ws_size,
                              hipStream_t stream)
{
    const float* query = (const float*)d_in[0];
    const float* key   = (const float*)d_in[1];
    const float* value = (const float*)d_in[2];
    const float* cosE  = (const float*)d_in[3];
    const float* sinE  = (const float*)d_in[4];
    // d_in[5] = mask (tril; causality hard-coded)
    const float* Wq = (const float*)d_in[6];
    const float* bq = (const float*)d_in[7];
    const float* Wk = (const float*)d_in[8];
    const float* bk = (const float*)d_in[9];
    const float* Wv = (const float*)d_in[10];
    const float* bv = (const float*)d_in[11];
    const float* Wo = (const float*)d_in[12];
    const float* bo = (const float*)d_in[13];

    char* ws = (char*)d_ws;
    constexpr size_t MB = 1u << 20;
    short* Xq   = (short*)(ws + 0);          //  8 MB
    short* Wqt  = (short*)(ws + 24 * MB);    //  2 MB
    short* Wkt  = (short*)(ws + 26 * MB);    //  0.5 MB
    short* Wvt  = (short*)(ws + 26 * MB + 512 * 1024);  // 0.5 MB
    short* Wot  = (short*)(ws + 27 * MB);    //  2 MB
    short* Qp   = (short*)(ws + 29 * MB);    //  8 MB
    short* Kp   = (short*)(ws + 37 * MB);    //  2 MB
    short* VTp  = (short*)(ws + 39 * MB);    //  2 MB
    short* attn = (short*)(ws + 41 * MB);    //  8 MB  (end: 49 MB)
    // Partials alias the dead Xq region (flash runs after projections):
    short* PO   = (short*)(ws + 0);          // 20 MB
    float* ML   = (float*)(ws + 21 * MB);    // 1.25 MB (< 24 MB boundary)
    (void)ws_size;

    conv_q<<<4096, 256, 0, stream>>>(query, Xq);
    transp_all<<<2560, 256, 0, stream>>>(Wq, Wk, Wv, Wo, Wqt, Wkt, Wvt, Wot);
    gemm_qkv<<<768, 256, 0, stream>>>(Xq, key, value, Wqt, Wkt, Wvt,
                                      bq, bk, bv, cosE, sinE, Qp, Kp, VTp);
    flash_gqa10<<<1280, 256, 0, stream>>>(Qp, Kp, VTp, attn, PO, ML);
    combine_kernel<<<dim3(48, 32), 256, 0, stream>>>(PO, ML, attn);
    gemm_o<<<dim3(16, 32), 256, 0, stream>>>(attn, Wot, bo, (float*)d_out);
}

// Round 19
// 109.891 us; speedup vs baseline: 1.0611x; 1.0611x over previous
//
#include <hip/hip_runtime.h>
#include <hip/hip_bf16.h>

// Problem constants
constexpr int Bc  = 2;
constexpr int Tc  = 2048;
constexpr int Ec  = 1024;
constexpr int Hc  = 16;
constexpr int KVc = 4;
constexpr int Dc  = 64;
// G = Hc/KVc = 4

typedef short bf16x8 __attribute__((ext_vector_type(8)));
typedef short short4v __attribute__((ext_vector_type(4)));
typedef float f32x4  __attribute__((ext_vector_type(4)));
typedef float f32x16 __attribute__((ext_vector_type(16)));
typedef int   i32x4  __attribute__((ext_vector_type(4)));

__device__ inline short f2bf_bits(float f) {
    union { __hip_bfloat16 h; short s; } u;
    u.h = __float2bfloat16(f);
    return u.s;
}

__device__ inline float bf2f(short s) {
    union { short s16; __hip_bfloat16 h; } u;
    u.s16 = s;
    return __bfloat162float(u.h);
}

__device__ inline unsigned pkbf(float a, float b) {
    union { __hip_bfloat162 h2; unsigned u; } u;
    u.h2 = __float22bfloat162_rn(float2{a, b});
    return u.u;
}

__device__ inline float fexp2(float x) { return __builtin_exp2f(x); }

// v_permlane32_swap_b32 a, b:  a' = [a.lo | b.lo], b' = [a.hi | b.hi].
// ONLY safe when a and b hold provably-distinct values (round-8 lesson:
// equal inputs get register-coalesced and the swap corrupts).
__device__ inline void permswap(unsigned &a, unsigned &b) {
    asm volatile("v_permlane32_swap_b32 %0, %1" : "+v"(a), "+v"(b));
}

// global -> LDS async copy, 16B per lane. LDS dest must be wave-uniform base;
// HW writes base + lane*16. Global src is per-lane (pre-swizzled).
__device__ inline void gload16(const short* g, short* lds) {
    __builtin_amdgcn_global_load_lds(
        (const __attribute__((address_space(1))) unsigned int*)g,
        (__attribute__((address_space(3))) unsigned int*)lds,
        16, 0, 0);
}

// ---------------------------------------------------------------------------
// Merged prep kernel (one launch):
//  blocks 0..12287:      fp32 -> bf16 convert of query/key/value
//  blocks 12288..14847:  transpose+convert of the 4 weight matrices
// ---------------------------------------------------------------------------
__global__ __launch_bounds__(256) void prep_all(
    const float* __restrict__ q, const float* __restrict__ k,
    const float* __restrict__ v,
    short* __restrict__ Xq, short* __restrict__ Xk, short* __restrict__ Xv,
    const float* __restrict__ Wq, const float* __restrict__ Wk,
    const float* __restrict__ Wv, const float* __restrict__ Wo,
    short* __restrict__ Wqt, short* __restrict__ Wkt,
    short* __restrict__ Wvt, short* __restrict__ Wot)
{
    __shared__ float tile[32][33];
    if (blockIdx.x < 12288) {
        // ---- conv path ----
        const int range = blockIdx.x >> 12;          // 4096 blocks per tensor
        const int sub   = blockIdx.x & 4095;
        const float* x = range == 0 ? q : (range == 1 ? k : v);
        short*       y = range == 0 ? Xq : (range == 1 ? Xk : Xv);
        int i = (sub * 256 + threadIdx.x) * 4;
        float4 vv = *reinterpret_cast<const float4*>(x + i);
        short4v o;
        o[0] = f2bf_bits(vv.x);
        o[1] = f2bf_bits(vv.y);
        o[2] = f2bf_bits(vv.z);
        o[3] = f2bf_bits(vv.w);
        *reinterpret_cast<short4v*>(y + i) = o;
        return;
    }
    // ---- transpose path ----
    const int id = blockIdx.x - 12288;               // 0..2559
    const float* W; short* Wt; int N, bx, by;
    if (id < 1024)      { W = Wq; Wt = Wqt; N = 1024; bx = id & 31;          by = id >> 5; }
    else if (id < 1280) { W = Wk; Wt = Wkt; N = 256;  bx = (id - 1024) & 7;  by = (id - 1024) >> 3; }
    else if (id < 1536) { W = Wv; Wt = Wvt; N = 256;  bx = (id - 1280) & 7;  by = (id - 1280) >> 3; }
    else                { W = Wo; Wt = Wot; N = 1024; bx = (id - 1536) & 31; by = (id - 1536) >> 5; }
    const int K = 1024;
    int nb = bx * 32, kb = by * 32;
    int tx = threadIdx.x & 31, ty = threadIdx.x >> 5;   // ty 0..7
    #pragma unroll
    for (int j = 0; j < 4; ++j)
        tile[ty + j * 8][tx] = W[(size_t)(kb + ty + j * 8) * N + nb + tx];
    __syncthreads();
    #pragma unroll
    for (int j = 0; j < 4; ++j)
        Wt[(size_t)(nb + ty + j * 8) * K + kb + tx] = f2bf_bits(tile[tx][ty + j * 8]);
}

// ---------------------------------------------------------------------------
// 128x64-tile bf16 MFMA GEMM core (BK=64), 4 waves, each wave 64x32 quadrant.
// Staging via global_load_lds w16 with pre-swizzled source (rule #21).
// ---------------------------------------------------------------------------
#define GEMM_CORE(A_, Bt_, Kdim_)                                              \
    const int lane = threadIdx.x & 63;                                         \
    const int w    = threadIdx.x >> 6;                                         \
    const int wm   = w >> 1, wn = w & 1;                                       \
    const int rin  = lane >> 3;                                                \
    const int swc  = ((lane & 7) ^ rin) * 8;                                   \
    f32x4 acc[4][2] = {};                                                      \
    for (int k0 = 0; k0 < (Kdim_); k0 += 64) {                                 \
        _Pragma("unroll")                                                      \
        for (int i2 = 0; i2 < 4; ++i2) {                                       \
            const int r = w * 32 + i2 * 8;                                     \
            gload16((A_) + (size_t)(m0 + r + rin) * (Kdim_) + k0 + swc,        \
                    As + r * 64);                                              \
        }                                                                      \
        _Pragma("unroll")                                                      \
        for (int i2 = 0; i2 < 2; ++i2) {                                       \
            const int r = w * 16 + i2 * 8;                                     \
            gload16((Bt_) + (size_t)(n0 + r + rin) * (Kdim_) + k0 + swc,       \
                    Bs + r * 64);                                              \
        }                                                                      \
        __syncthreads();                                                       \
        _Pragma("unroll")                                                      \
        for (int ks = 0; ks < 2; ++ks) {                                       \
            bf16x8 af[4], bfr[2];                                              \
            _Pragma("unroll")                                                  \
            for (int mi = 0; mi < 4; ++mi) {                                   \
                int row = wm * 64 + mi * 16 + (lane & 15);                     \
                int sl  = (ks * 4 + (lane >> 4)) ^ (row & 7);                  \
                af[mi] = *reinterpret_cast<const bf16x8*>(As + row * 64 + sl * 8); \
            }                                                                  \
            _Pragma("unroll")                                                  \
            for (int ni = 0; ni < 2; ++ni) {                                   \
                int row = wn * 32 + ni * 16 + (lane & 15);                     \
                int sl  = (ks * 4 + (lane >> 4)) ^ (row & 7);                  \
                bfr[ni] = *reinterpret_cast<const bf16x8*>(Bs + row * 64 + sl * 8); \
            }                                                                  \
            _Pragma("unroll")                                                  \
            for (int mi = 0; mi < 4; ++mi)                                     \
                _Pragma("unroll")                                              \
                for (int ni = 0; ni < 2; ++ni)                                 \
                    acc[mi][ni] = __builtin_amdgcn_mfma_f32_16x16x32_bf16(     \
                        af[mi], bfr[ni], acc[mi][ni], 0, 0, 0);                \
        }                                                                      \
        __syncthreads();                                                       \
    }

// ---------------------------------------------------------------------------
// Grouped Q/K/V projection GEMM with FUSED RoPE epilogue for Q and K.
// Output N-tiles are head-aligned (64 cols = one head's d 0..63), so the
// (d, d+32) rope pairing is block-local: dump tile to LDS (As, dead after
// the main loop), barrier, rope with float4 cos/sin loads, store.
// Q additionally scaled by 1/sqrt(D)*log2e (exp2-domain softmax).
// ---------------------------------------------------------------------------
__global__ __launch_bounds__(256) void gemm_qkv(
    const short* __restrict__ Xq, const short* __restrict__ Xk,
    const short* __restrict__ Xv,
    const short* __restrict__ Wqt, const short* __restrict__ Wkt,
    const short* __restrict__ Wvt,
    const float* __restrict__ bq, const float* __restrict__ bk,
    const float* __restrict__ bv,
    const float* __restrict__ cosE, const float* __restrict__ sinE,
    short* __restrict__ Qp, short* __restrict__ Kp, short* __restrict__ VTp)
{
    __shared__ short As[128 * 64];
    __shared__ short Bs[64 * 64];
    const int gid = blockIdx.x;
    const short *A, *Bt; const float* bias; int bx, by, mode;
    if (gid < 512)      { mode = 0; A = Xq; Bt = Wqt; bias = bq; bx = gid & 15;         by = gid >> 4; }
    else if (gid < 640) { mode = 1; A = Xk; Bt = Wkt; bias = bk; bx = (gid - 512) & 3;  by = (gid - 512) >> 2; }
    else                { mode = 2; A = Xv; Bt = Wvt; bias = bv; bx = (gid - 640) & 3;  by = (gid - 640) >> 2; }
    const int m0 = by * 128, n0 = bx * 64;

    GEMM_CORE(A, Bt, 1024)

    if (mode == 2) {
        // V: transposed store (no rope)
        #pragma unroll
        for (int mi = 0; mi < 4; ++mi)
            #pragma unroll
            for (int ni = 0; ni < 2; ++ni) {
                int col = n0 + wn * 32 + ni * 16 + (lane & 15);
                float bv2 = bias[col];
                #pragma unroll
                for (int i = 0; i < 4; ++i) {
                    int row = m0 + wm * 64 + mi * 16 + ((lane >> 4) * 4) + i;
                    VTp[(((size_t)(row >> 11) * 256 + col) << 11) + (row & 2047)]
                        = f2bf_bits(acc[mi][ni][i] + bv2);
                }
            }
        return;
    }

    // Q/K: dump tile (post-bias, bf16) into As, then fused rope.
    #pragma unroll
    for (int mi = 0; mi < 4; ++mi)
        #pragma unroll
        for (int ni = 0; ni < 2; ++ni) {
            int cl = wn * 32 + ni * 16 + (lane & 15);
            float bv2 = bias[n0 + cl];
            #pragma unroll
            for (int i = 0; i < 4; ++i) {
                int rl = wm * 64 + mi * 16 + ((lane >> 4) * 4) + i;
                As[rl * 64 + cl] = f2bf_bits(acc[mi][ni][i] + bv2);
            }
        }
    __syncthreads();

    const float scale = (mode == 0) ? 0.125f * 1.44269504089f : 1.0f;
    short* outp = (mode == 0) ? Qp : Kp;
    const int ldo = (mode == 0) ? 1024 : 256;
    const int dg  = (threadIdx.x & 7) * 4;     // d group 0..28
    const int rb  = threadIdx.x >> 3;          // row base 0..31
    #pragma unroll
    for (int rr = 0; rr < 4; ++rr) {
        int rl = rb + rr * 32;
        int t  = (m0 + rl) & (Tc - 1);
        float4 c4 = *reinterpret_cast<const float4*>(cosE + t * 64 + dg);
        float4 s4 = *reinterpret_cast<const float4*>(sinE + t * 64 + dg);
        short4v a = *reinterpret_cast<const short4v*>(As + rl * 64 + dg);
        short4v b = *reinterpret_cast<const short4v*>(As + rl * 64 + 32 + dg);
        float c[4] = {c4.x, c4.y, c4.z, c4.w};
        float s[4] = {s4.x, s4.y, s4.z, s4.w};
        short4v oa, ob;
        #pragma unroll
        for (int j = 0; j < 4; ++j) {
            float x1 = bf2f(a[j]), x2 = bf2f(b[j]);
            oa[j] = f2bf_bits((x1 * c[j] - x2 * s[j]) * scale);
            ob[j] = f2bf_bits((x2 * c[j] + x1 * s[j]) * scale);
        }
        size_t go = (size_t)(m0 + rl) * ldo + n0 + dg;
        *reinterpret_cast<short4v*>(outp + go)      = oa;
        *reinterpret_cast<short4v*>(outp + go + 32) = ob;
    }
}

// O-projection GEMM: attn @ Wot + bo -> fp32 out
__global__ __launch_bounds__(256) void gemm_o(
    const short* __restrict__ A, const short* __restrict__ Bt,
    const float* __restrict__ bias, float* __restrict__ C)
{
    __shared__ short As[128 * 64];
    __shared__ short Bs[64 * 64];
    const int m0 = blockIdx.y * 128, n0 = blockIdx.x * 64;

    GEMM_CORE(A, Bt, 1024)

    #pragma unroll
    for (int mi = 0; mi < 4; ++mi)
        #pragma unroll
        for (int ni = 0; ni < 2; ++ni) {
            int col = n0 + wn * 32 + ni * 16 + (lane & 15);
            float bv2 = bias[col];
            #pragma unroll
            for (int i = 0; i < 4; ++i) {
                int row = m0 + wm * 64 + mi * 16 + ((lane >> 4) * 4) + i;
                C[(size_t)row * 1024 + col] = acc[mi][ni][i] + bv2;
            }
        }
}

// ---------------------------------------------------------------------------
// Causal GQA flash attention (round-12 proven version, unchanged):
// per-slice K/V ds_reads (64 VGPR + 64 acc = 128 regs), permswap pack,
// launch_bounds(256,4) -> 4 waves/SIMD co-resident, 2-buffer staging.
// ---------------------------------------------------------------------------
__global__ __launch_bounds__(256, 4) void flash_gqa10(
    const short* __restrict__ Q,   // [B*T][H*D]  post-RoPE, pre-scaled
    const short* __restrict__ Kx,  // [B*T][KV*D] post-RoPE
    const short* __restrict__ VT,  // [B*KV][D][T]
    short* __restrict__ attn,      // [B*T][H*D]
    short* __restrict__ PO,        // partial O (bf16)
    float* __restrict__ ML)        // partial (m, l) f32
{
    __shared__ short smem[16384];  // 32KB: K dbuf [0,8192), V dbuf [8192,16384)

    const int lane = threadIdx.x & 63;
    const int w    = threadIdx.x >> 6;
    const int lo   = lane & 31;
    const int hi   = lane >> 5;

    // Decode: XCD owns one (b,kvh); j enumerates (g, chunk-unit), heavy first.
    const int L   = blockIdx.x;          // 0..1279
    const int xcd = L & 7;
    const int j   = L >> 3;              // 0..159
    const int g   = j & 3;
    const int u   = 39 - (j >> 2);       // 0..39, compact (qt, c) index
    int qt = 0, rem = u;
    while (true) { int nc0 = (qt >> 2) + 1; if (rem < nc0) break; rem -= nc0; ++qt; }
    const int c  = rem;
    const int nc = (qt >> 2) + 1;
    const int b   = xcd >> 2;
    const int kvh = xcd & 3;
    const int h   = kvh * 4 + g;
    const int slot = (b * 16 + h) * 40 + u;

    const int q0w = qt * 128 + w * 32;
    const int qg  = q0w + lo;

    // Q B-fragments (persistent, 16 VGPR)
    bf16x8 qf[4];
    {
        const short* qp = Q + (size_t)(b * Tc + qg) * Ec + h * 64 + hi * 8;
        #pragma unroll
        for (int ds = 0; ds < 4; ++ds)
            qf[ds] = *reinterpret_cast<const bf16x8*>(qp + 16 * ds);
    }
    const short* Kb = Kx + (size_t)b * Tc * (KVc * Dc) + kvh * 64;
    const short* Vb = VT + (size_t)(b * KVc + kvh) * 64 * Tc;

    const int rin = lane >> 3;
    const int swc = ((lane & 7) ^ rin) * 8;
    auto stage = [&](int bufi, int kb2) {
        #pragma unroll
        for (int i2 = 0; i2 < 2; ++i2) {
            const int row = w * 16 + i2 * 8;
            gload16(Kb + (size_t)(kb2 + row + rin) * 256 + swc,
                    smem + bufi * 4096 + row * 64);
            gload16(Vb + (size_t)(row + rin) * Tc + kb2 + swc,
                    smem + 8192 + bufi * 4096 + row * 64);
        }
    };

    // hoisted LDS fragment offsets: frag(a, i) at lo*64 + 2048*a + slot8[i]
    int slot8[4];
    #pragma unroll
    for (int i = 0; i < 4; ++i)
        slot8[i] = (((2 * i + hi) ^ (lo & 7)) * 8) + lo * 64;

    const int t0 = c * 8;
    const int t1 = min(c * 8 + 8, 2 * qt + 2);
    stage(0, t0 * 64);

    float m = -1e30f, l = 0.f;
    f32x16 o0 = {}, o1 = {};
    const int kv_hi = q0w + 32;

    for (int t = t0; t < t1; ++t) {
        const int kb  = t * 64;
        const int cur = (t - t0) & 1;
        // my tile-t rows landed; after barrier, everyone's have.
        asm volatile("s_waitcnt vmcnt(0)" ::: "memory");
        __builtin_amdgcn_s_barrier();
        // issue next tile (writes buf cur^1; all waves are past their reads of it)
        if (t + 1 < t1) stage(cur ^ 1, kb + 64);

        if (kb < kv_hi) {
            const short* Kl = smem + cur * 4096;
            const short* Vl = Kl + 8192;

            // S^T = K Q^T  (per-slice K loads: 8 transient regs)
            f32x16 s0 = {}, s1 = {};
            __builtin_amdgcn_s_setprio(1);
            #pragma unroll
            for (int ds = 0; ds < 4; ++ds) {
                bf16x8 k0 = *reinterpret_cast<const bf16x8*>(Kl + slot8[ds]);
                bf16x8 k1 = *reinterpret_cast<const bf16x8*>(Kl + slot8[ds] + 2048);
                s0 = __builtin_amdgcn_mfma_f32_32x32x16_bf16(k0, qf[ds], s0, 0, 0, 0);
                s1 = __builtin_amdgcn_mfma_f32_32x32x16_bf16(k1, qf[ds], s1, 0, 0, 0);
            }
            __builtin_amdgcn_s_setprio(0);

            // causal mask (diagonal tiles only)
            if (kb + 63 > q0w) {
                #pragma unroll
                for (int r = 0; r < 16; ++r) {
                    int kkl = (r & 3) + 8 * (r >> 2) + 4 * hi;
                    if (kb + kkl > qg)      s0[r] = -1e30f;
                    if (kb + 32 + kkl > qg) s1[r] = -1e30f;
                }
            }

            // online softmax: tree max, defer-max (T13), exp2 domain
            float mx[8];
            #pragma unroll
            for (int j2 = 0; j2 < 8; ++j2)
                mx[j2] = fmaxf(fmaxf(s0[2 * j2], s0[2 * j2 + 1]),
                               fmaxf(s1[2 * j2], s1[2 * j2 + 1]));
            #pragma unroll
            for (int st = 4; st > 0; st >>= 1)
                #pragma unroll
                for (int j2 = 0; j2 < st; ++j2) mx[j2] = fmaxf(mx[j2], mx[j2 + st]);
            float pm = fmaxf(mx[0], __shfl_xor(mx[0], 32));

            float corr = 1.0f;
            if (__any(pm > m + 8.0f)) {
                float mn = fmaxf(m, pm);
                corr = fexp2(m - mn);
                m = mn;
                #pragma unroll
                for (int r = 0; r < 16; ++r) { o0[r] *= corr; o1[r] *= corr; }
            }
            float rs = 0.f;
            #pragma unroll
            for (int r = 0; r < 16; ++r) {
                s0[r] = fexp2(s0[r] - m);
                s1[r] = fexp2(s1[r] - m);
                rs += s0[r] + s1[r];
            }
            rs += __shfl_xor(rs, 32);
            l = l * corr + rs;

            // pack P via permlane32_swap (distinct operands; 8 transient regs)
            // + per-slice V loads (8 transient regs) — keeps peak <= 128.
            #pragma unroll
            for (int t2 = 0; t2 < 2; ++t2) {
                const f32x16& sv = t2 ? s1 : s0;
                unsigned pw[8];
                #pragma unroll
                for (int j2 = 0; j2 < 8; ++j2)
                    pw[j2] = pkbf(sv[2 * j2], sv[2 * j2 + 1]);
                #pragma unroll
                for (int u2 = 0; u2 < 2; ++u2) {
                    permswap(pw[4 * u2 + 0], pw[4 * u2 + 2]);
                    permswap(pw[4 * u2 + 1], pw[4 * u2 + 3]);
                    union { unsigned u4[4]; bf16x8 v; } pf;
                    pf.u4[0] = pw[4 * u2 + 0];
                    pf.u4[1] = pw[4 * u2 + 1];
                    pf.u4[2] = pw[4 * u2 + 2];
                    pf.u4[3] = pw[4 * u2 + 3];
                    int sl = 2 * t2 + u2;
                    bf16x8 v0 = *reinterpret_cast<const bf16x8*>(Vl + slot8[sl]);
                    bf16x8 v1 = *reinterpret_cast<const bf16x8*>(Vl + slot8[sl] + 2048);
                    __builtin_amdgcn_s_setprio(1);
                    o0 = __builtin_amdgcn_mfma_f32_32x32x16_bf16(v0, pf.v, o0, 0, 0, 0);
                    o1 = __builtin_amdgcn_mfma_f32_32x32x16_bf16(v1, pf.v, o1, 0, 0, 0);
                    __builtin_amdgcn_s_setprio(0);
                }
            }
        }
    }
    // all waves past their final reads before obuf overwrites K/V region
    __builtin_amdgcn_s_barrier();

    // epilogue: transpose O^T via LDS -> coalesced global stores
    const float inv = (nc == 1) ? (1.0f / l) : 1.0f;
    short* ob = smem + w * 2048;
    #pragma unroll
    for (int r = 0; r < 16; ++r) {
        int d0 = (r & 3) + 8 * (r >> 2) + 4 * hi;
        ob[lo * 64 + ( d0       ^ ((lo & 7) << 3))] = f2bf_bits(o0[r] * inv);
        ob[lo * 64 + ((d0 + 32) ^ ((lo & 7) << 3))] = f2bf_bits(o1[r] * inv);
    }
    if (nc > 1 && hi == 0) {
        ML[(size_t)slot * 256 + (w * 32 + lo) * 2]     = m;
        ML[(size_t)slot * 256 + (w * 32 + lo) * 2 + 1] = l;
    }
    #pragma unroll
    for (int j2 = 0; j2 < 4; ++j2) {
        int row = lane >> 1;
        int c8  = ((lane & 1) * 4 + j2) * 8;
        bf16x8 v = *reinterpret_cast<const bf16x8*>(
            ob + row * 64 + (c8 ^ ((row & 7) << 3)));
        if (nc == 1)
            *reinterpret_cast<bf16x8*>(
                attn + (size_t)(b * Tc + q0w + row) * Ec + h * 64 + c8) = v;
        else
            *reinterpret_cast<bf16x8*>(
                PO + (size_t)slot * 8192 + (w * 32 + row) * 64 + c8) = v;
    }
}

// ---------------------------------------------------------------------------
// combine partials: for qt >= 4 merge nc chunks -> attn (vectorized).
// ---------------------------------------------------------------------------
__global__ __launch_bounds__(256) void combine_kernel(
    const short* __restrict__ PO, const float* __restrict__ ML,
    short* __restrict__ attn)
{
    const int qt    = 4 + (blockIdx.x >> 2);   // 4..15
    const int rg    = blockIdx.x & 3;          // row-group of 32
    const int combo = blockIdx.y;              // 0..31
    const int h = combo & 15, b = combo >> 4;
    const int nc = (qt >> 2) + 1;              // 2..4
    const int k  = qt >> 2, r4 = qt & 3;
    const int base = (k + 1) * (2 * k + r4);   // sum of nc for qt' < qt
    const int slot0 = combo * 40 + base;

    const int r  = rg * 32 + (threadIdx.x >> 3);   // row 0..127
    const int d8 = (threadIdx.x & 7) * 8;          // d group

    float mv[4], lv[4];
    float M = -1e30f;
    #pragma unroll 4
    for (int cc = 0; cc < nc; ++cc) {
        mv[cc] = ML[(size_t)(slot0 + cc) * 256 + r * 2];
        lv[cc] = ML[(size_t)(slot0 + cc) * 256 + r * 2 + 1];
        M = fmaxf(M, mv[cc]);
    }
    float Lsum = 0.f;
    float a[8] = {};
    #pragma unroll 4
    for (int cc = 0; cc < nc; ++cc) {
        float wgt = fexp2(mv[cc] - M);
        Lsum += wgt * lv[cc];
        bf16x8 po = *reinterpret_cast<const bf16x8*>(
            PO + (size_t)(slot0 + cc) * 8192 + r * 64 + d8);
        #pragma unroll
        for (int j = 0; j < 8; ++j) a[j] += wgt * bf2f(po[j]);
    }
    float inv = 1.0f / Lsum;
    bf16x8 o;
    #pragma unroll
    for (int j = 0; j < 8; ++j) o[j] = f2bf_bits(a[j] * inv);
    *reinterpret_cast<bf16x8*>(
        attn + (size_t)(b * Tc + qt * 128 + r) * Ec + h * 64 + d8) = o;
}

// ---------------------------------------------------------------------------
extern "C" void kernel_launch(void* const* d_in, const int* in_sizes, int n_in,
                              void* d_out, int out_size, void* d_ws, size_t ws_size,
                              hipStream_t stream)
{
    const float* query = (const float*)d_in[0];
    const float* key   = (const float*)d_in[1];
    const float* value = (const float*)d_in[2];
    const float* cosE  = (const float*)d_in[3];
    const float* sinE  = (const float*)d_in[4];
    // d_in[5] = mask (tril; causality hard-coded)
    const float* Wq = (const float*)d_in[6];
    const float* bq = (const float*)d_in[7];
    const float* Wk = (const float*)d_in[8];
    const float* bk = (const float*)d_in[9];
    const float* Wv = (const float*)d_in[10];
    const float* bv = (const float*)d_in[11];
    const float* Wo = (const float*)d_in[12];
    const float* bo = (const float*)d_in[13];

    char* ws = (char*)d_ws;
    constexpr size_t MB = 1u << 20;
    short* Xq   = (short*)(ws + 0);          //  8 MB
    short* Xk   = (short*)(ws + 8  * MB);    //  8 MB
    short* Xv   = (short*)(ws + 16 * MB);    //  8 MB
    short* Wqt  = (short*)(ws + 24 * MB);    //  2 MB
    short* Wkt  = (short*)(ws + 26 * MB);    //  0.5 MB
    short* Wvt  = (short*)(ws + 26 * MB + 512 * 1024);  // 0.5 MB
    short* Wot  = (short*)(ws + 27 * MB);    //  2 MB
    short* Qp   = (short*)(ws + 29 * MB);    //  8 MB
    short* Kp   = (short*)(ws + 37 * MB);    //  2 MB
    short* VTp  = (short*)(ws + 39 * MB);    //  2 MB
    short* attn = (short*)(ws + 41 * MB);    //  8 MB  (end: 49 MB)
    // Partials alias the dead Xq/Xk/Xv region (flash runs after projections):
    short* PO   = (short*)(ws + 0);          // 20 MB
    float* ML   = (float*)(ws + 21 * MB);    // 1.25 MB (< 24 MB boundary)
    (void)ws_size;

    prep_all<<<14848, 256, 0, stream>>>(query, key, value, Xq, Xk, Xv,
                                        Wq, Wk, Wv, Wo, Wqt, Wkt, Wvt, Wot);
    gemm_qkv<<<768, 256, 0, stream>>>(Xq, Xk, Xv, Wqt, Wkt, Wvt,
                                      bq, bk, bv, cosE, sinE, Qp, Kp, VTp);
    flash_gqa10<<<1280, 256, 0, stream>>>(Qp, Kp, VTp, attn, PO, ML);
    combine_kernel<<<dim3(48, 32), 256, 0, stream>>>(PO, ML, attn);
    gemm_o<<<dim3(16, 32), 256, 0, stream>>>(attn, Wot, bo, (float*)d_out);
}